// Round 2
// baseline (4781.546 us; speedup 1.0000x reference)
//
#include <hip/hip_runtime.h>

#define DIMC 1024
#define SEQ  2048
#define NHEAD 16
#define BATCH 8

// ---------------------------------------------------------------- helpers
__device__ __forceinline__ void gll4(const float* g, float* l) {
  // async global->LDS, 4B per lane, dest = wave-uniform base + lane*4
  __builtin_amdgcn_global_load_lds(
      (const __attribute__((address_space(1))) void*)g,
      (__attribute__((address_space(3))) void*)l, 4, 0, 0);
}

// waitcnt immediates (gfx9 encoding: vm[3:0]=b3:0, exp=b6:4, lgkm=b11:8, vm[5:4]=b15:14)
// Ring math: PD=8 slots x 3 loads/step per wave. When consuming slot t, the loads
// issued after slot-t's trio are exactly 3*(PD-1)=21 -> must wait vmcnt<=21.
// (Round-1 bug: vm<=29 was a no-op since in-flight never exceeds ~24 -> stale LDS race.)
#define WAIT_VM21   0x4F75  // vmcnt<=21 (vm[3:0]=5, vm[5:4]=1), lgkm/exp don't-care
#define WAIT_VM0    0x0F70  // vmcnt<=0
#define WAIT_LGKM0  0xC07F  // lgkmcnt<=0 only

// ---------------------------------------------------------------- pack Wa/Wb into padded 128x1024
__global__ void pack_ab_kernel(const float* __restrict__ Wa, const float* __restrict__ ba,
                               const float* __restrict__ Wb, const float* __restrict__ bb,
                               float* __restrict__ Wab, float* __restrict__ bab)
{
  int i = blockIdx.x * 256 + threadIdx.x;
  if (i < 128 * 1024) {
    int row = i >> 10, col = i & 1023;
    float v = 0.0f;
    if (row < 16) v = Wa[(row << 10) + col];
    else if (row < 32) v = Wb[((row - 16) << 10) + col];
    Wab[i] = v;
  } else {
    int j = i - 128 * 1024;
    if (j < 128) {
      float v = 0.0f;
      if (j < 16) v = ba[j];
      else if (j < 32) v = bb[j - 16];
      bab[j] = v;
    }
  }
}

// ---------------------------------------------------------------- SGEMM: C = act(A @ B^T + bias)
// A: M x K row-major, B: N x K row-major (rows = output features). M,N multiples of 128, K of 16.
#define BM 128
#define BN 128
#define BKT 16
#define LDT (BM + 4)

__global__ __launch_bounds__(256, 2)
void sgemm_kernel(const float* __restrict__ A, const float* __restrict__ B,
                  const float* __restrict__ bias, float* __restrict__ C,
                  int K, int ldc, int nvalid, int act)
{
  __shared__ float As[BKT][LDT];
  __shared__ float Bs[BKT][LDT];
  const int tid  = threadIdx.x;
  const int row  = tid >> 1;          // 0..127
  const int koff = (tid & 1) << 3;    // 0 or 8
  const int tx = tid & 15, ty = tid >> 4;
  const float* Ag = A + (size_t)(blockIdx.x * BM + row) * K + koff;
  const float* Bg = B + (size_t)(blockIdx.y * BN + row) * K + koff;
  float4 a0 = *(const float4*)(Ag);
  float4 a1 = *(const float4*)(Ag + 4);
  float4 b0 = *(const float4*)(Bg);
  float4 b1 = *(const float4*)(Bg + 4);
  float acc[8][8];
  #pragma unroll
  for (int i = 0; i < 8; ++i)
    #pragma unroll
    for (int j = 0; j < 8; ++j) acc[i][j] = 0.0f;

  for (int kt = 0; kt < K; kt += BKT) {
    __syncthreads();  // previous compute done reading LDS
    As[koff+0][row] = a0.x; As[koff+1][row] = a0.y; As[koff+2][row] = a0.z; As[koff+3][row] = a0.w;
    As[koff+4][row] = a1.x; As[koff+5][row] = a1.y; As[koff+6][row] = a1.z; As[koff+7][row] = a1.w;
    Bs[koff+0][row] = b0.x; Bs[koff+1][row] = b0.y; Bs[koff+2][row] = b0.z; Bs[koff+3][row] = b0.w;
    Bs[koff+4][row] = b1.x; Bs[koff+5][row] = b1.y; Bs[koff+6][row] = b1.z; Bs[koff+7][row] = b1.w;
    __syncthreads();
    if (kt + BKT < K) {  // prefetch next tile into regs; overlaps compute below
      a0 = *(const float4*)(Ag + kt + BKT);
      a1 = *(const float4*)(Ag + kt + BKT + 4);
      b0 = *(const float4*)(Bg + kt + BKT);
      b1 = *(const float4*)(Bg + kt + BKT + 4);
    }
    #pragma unroll
    for (int kk = 0; kk < BKT; ++kk) {
      float4 af0 = *(const float4*)&As[kk][ty << 3];
      float4 af1 = *(const float4*)&As[kk][(ty << 3) + 4];
      float4 bf0 = *(const float4*)&Bs[kk][tx << 3];
      float4 bf1 = *(const float4*)&Bs[kk][(tx << 3) + 4];
      float am[8] = {af0.x, af0.y, af0.z, af0.w, af1.x, af1.y, af1.z, af1.w};
      float bv[8] = {bf0.x, bf0.y, bf0.z, bf0.w, bf1.x, bf1.y, bf1.z, bf1.w};
      #pragma unroll
      for (int i = 0; i < 8; ++i)
        #pragma unroll
        for (int j = 0; j < 8; ++j)
          acc[i][j] = fmaf(am[i], bv[j], acc[i][j]);
    }
  }
  const int m0 = blockIdx.x * BM + (ty << 3);
  const int n0 = blockIdx.y * BN + (tx << 3);
  #pragma unroll
  for (int i = 0; i < 8; ++i) {
    float* Cr = C + (size_t)(m0 + i) * ldc;
    #pragma unroll
    for (int j = 0; j < 8; ++j) {
      int n = n0 + j;
      if (n < nvalid) {
        float val = acc[i][j] + bias[n];
        if (act == 1)      val = val * (1.0f / (1.0f + __expf(-val)));   // silu
        else if (act == 2) val = 1.0f / (1.0f + __expf(-val));            // sigmoid
        Cr[n] = val;
      }
    }
  }
}

// ---------------------------------------------------------------- depthwise conv(K=4,pad2,[:n]) + silu + optional l2norm
// y[t,c] = silu( sum_j x[t-2+j, c] * w[c,j] ), then (q,k): y /= (||y||_2(over 1024) + 1e-6)
__global__ __launch_bounds__(256)
void conv_kernel(const float* __restrict__ pre, const float* __restrict__ w,
                 float* __restrict__ out, int do_norm)
{
  __shared__ float red[4];
  const int bt  = blockIdx.x;          // b_local*SEQ + t
  const int t   = bt & (SEQ - 1);
  const int tid = threadIdx.x;
  const int c   = tid << 2;
  const float* rowp = pre + (size_t)bt * DIMC + c;
  const float4 z = make_float4(0.f, 0.f, 0.f, 0.f);
  float4 xm2 = (t >= 2)      ? *(const float4*)(rowp - 2 * DIMC) : z;
  float4 xm1 = (t >= 1)      ? *(const float4*)(rowp - DIMC)     : z;
  float4 x0  =                 *(const float4*)(rowp);
  float4 xp1 = (t + 1 < SEQ) ? *(const float4*)(rowp + DIMC)     : z;
  const float4 w0 = *(const float4*)(w + (size_t)(c + 0) * 4);
  const float4 w1 = *(const float4*)(w + (size_t)(c + 1) * 4);
  const float4 w2 = *(const float4*)(w + (size_t)(c + 2) * 4);
  const float4 w3 = *(const float4*)(w + (size_t)(c + 3) * 4);
  float y0 = xm2.x * w0.x + xm1.x * w0.y + x0.x * w0.z + xp1.x * w0.w;
  float y1 = xm2.y * w1.x + xm1.y * w1.y + x0.y * w1.z + xp1.y * w1.w;
  float y2 = xm2.z * w2.x + xm1.z * w2.y + x0.z * w2.z + xp1.z * w2.w;
  float y3 = xm2.w * w3.x + xm1.w * w3.y + x0.w * w3.z + xp1.w * w3.w;
  y0 = y0 * (1.0f / (1.0f + __expf(-y0)));
  y1 = y1 * (1.0f / (1.0f + __expf(-y1)));
  y2 = y2 * (1.0f / (1.0f + __expf(-y2)));
  y3 = y3 * (1.0f / (1.0f + __expf(-y3)));
  if (do_norm) {
    float ss = y0*y0 + y1*y1 + y2*y2 + y3*y3;
    #pragma unroll
    for (int off = 32; off >= 1; off >>= 1) ss += __shfl_xor(ss, off);
    if ((tid & 63) == 0) red[tid >> 6] = ss;
    __syncthreads();
    float tot = red[0] + red[1] + red[2] + red[3];
    float rn = 1.0f / (sqrtf(tot) + 1e-6f);
    y0 *= rn; y1 *= rn; y2 *= rn; y3 *= rn;
  }
  *(float4*)(out + (size_t)bt * DIMC + c) = make_float4(y0, y1, y2, y3);
}

// ---------------------------------------------------------------- gated delta scan
// Per (b,h): S_t = a*S + coef*k^T (coef = b*v - a*b*(S k)); o_t = S_t^T q.
// 256 threads: thread (r=tid>>2, g=tid&3) owns S[r][16g..16g+16) and T[r][16g..16g+16), T = S^T.
#define PD 8
__global__ __launch_bounds__(256, 1)
void scan_kernel(const float* __restrict__ q, const float* __restrict__ k,
                 const float* __restrict__ v, const float* __restrict__ ab,
                 float* __restrict__ O)
{
  __shared__ float ring[PD][3][64];   // per-step q,k,v rows
  __shared__ float coefs[2][64];
  __shared__ float aS[SEQ];
  __shared__ float bSh[SEQ];
  const int bh  = blockIdx.x;
  const int b   = bh >> 4, h = bh & 15;
  const int tid = threadIdx.x;
  const int r   = tid >> 2, g = tid & 3;
  const int lane = tid & 63;

  const float* abbase = ab + (size_t)b * SEQ * 32 + h;
  for (int i = tid; i < SEQ; i += 256) {
    aS[i]  = abbase[(size_t)i * 32];
    bSh[i] = abbase[(size_t)i * 32 + 16];
  }
  __syncthreads();

  const size_t base = (size_t)b * SEQ * DIMC + h * 64;
  const float* qp = q + base + lane;
  const float* kp = k + base + lane;
  const float* vp = v + base + lane;

  #pragma unroll
  for (int pt = 0; pt < PD; ++pt) {
    gll4(qp + (size_t)pt * DIMC, &ring[pt][0][0]);
    gll4(kp + (size_t)pt * DIMC, &ring[pt][1][0]);
    gll4(vp + (size_t)pt * DIMC, &ring[pt][2][0]);
  }

  float S[16], T[16];
  #pragma unroll
  for (int j = 0; j < 16; ++j) { S[j] = 0.f; T[j] = 0.f; }
  float* Ob = O + base;
  int p = 0;

  for (int t = 0; t < SEQ; ++t) {
    const int slot = t & (PD - 1);
    if (t < SEQ - PD) { __builtin_amdgcn_s_waitcnt(WAIT_VM21); }
    else              { __builtin_amdgcn_s_waitcnt(WAIT_VM0);  }
    asm volatile("" ::: "memory");

    const float a  = aS[t];
    const float bg = bSh[t];
    const float4 k0 = *(const float4*)&ring[slot][1][(g << 4) + 0];
    const float4 k1 = *(const float4*)&ring[slot][1][(g << 4) + 4];
    const float4 k2 = *(const float4*)&ring[slot][1][(g << 4) + 8];
    const float4 k3 = *(const float4*)&ring[slot][1][(g << 4) + 12];
    const float4 q0 = *(const float4*)&ring[slot][0][(g << 4) + 0];
    const float4 q1 = *(const float4*)&ring[slot][0][(g << 4) + 4];
    const float4 q2 = *(const float4*)&ring[slot][0][(g << 4) + 8];
    const float4 q3 = *(const float4*)&ring[slot][0][(g << 4) + 12];
    const float vd = ring[slot][2][r];
    const float ke = ring[slot][1][r];
    const float kk[16] = {k0.x,k0.y,k0.z,k0.w, k1.x,k1.y,k1.z,k1.w,
                          k2.x,k2.y,k2.z,k2.w, k3.x,k3.y,k3.z,k3.w};
    const float qq[16] = {q0.x,q0.y,q0.z,q0.w, q1.x,q1.y,q1.z,q1.w,
                          q2.x,q2.y,q2.z,q2.w, q3.x,q3.y,q3.z,q3.w};

    float sk = 0.f;
    #pragma unroll
    for (int j = 0; j < 16; ++j) sk = fmaf(S[j], kk[j], sk);
    sk += __shfl_xor(sk, 1);
    sk += __shfl_xor(sk, 2);
    const float coef = bg * vd - a * bg * sk;
    if (g == 0) coefs[p][r] = coef;

    // raw barrier: drain LDS only, keep async ring loads in flight
    asm volatile("" ::: "memory");
    __builtin_amdgcn_s_waitcnt(WAIT_LGKM0);
    __builtin_amdgcn_s_barrier();
    asm volatile("" ::: "memory");

    if (t + PD < SEQ) {  // refill the slot everyone is done reading
      gll4(qp + (size_t)(t + PD) * DIMC, &ring[slot][0][0]);
      gll4(kp + (size_t)(t + PD) * DIMC, &ring[slot][1][0]);
      gll4(vp + (size_t)(t + PD) * DIMC, &ring[slot][2][0]);
    }

    const float4 c0 = *(const float4*)&coefs[p][(g << 4) + 0];
    const float4 c1 = *(const float4*)&coefs[p][(g << 4) + 4];
    const float4 c2 = *(const float4*)&coefs[p][(g << 4) + 8];
    const float4 c3 = *(const float4*)&coefs[p][(g << 4) + 12];
    const float cc[16] = {c0.x,c0.y,c0.z,c0.w, c1.x,c1.y,c1.z,c1.w,
                          c2.x,c2.y,c2.z,c2.w, c3.x,c3.y,c3.z,c3.w};
    float o = 0.f;
    #pragma unroll
    for (int j = 0; j < 16; ++j) {
      S[j] = fmaf(a, S[j], coef * kk[j]);
      float tj = fmaf(a, T[j], ke * cc[j]);
      T[j] = tj;
      o = fmaf(qq[j], tj, o);
    }
    o += __shfl_xor(o, 1);
    o += __shfl_xor(o, 2);
    if (g == 0) Ob[(size_t)t * DIMC + r] = o;
    p ^= 1;
  }
}

// ---------------------------------------------------------------- host
extern "C" void kernel_launch(void* const* d_in, const int* in_sizes, int n_in,
                              void* d_out, int out_size, void* d_ws, size_t ws_size,
                              hipStream_t stream)
{
  const float* x  = (const float*)d_in[0];
  const float* Wq = (const float*)d_in[1];
  const float* bq = (const float*)d_in[2];
  const float* Wk = (const float*)d_in[3];
  const float* bk = (const float*)d_in[4];
  const float* Wv = (const float*)d_in[5];
  const float* bv = (const float*)d_in[6];
  const float* Wa = (const float*)d_in[7];
  const float* ba = (const float*)d_in[8];
  const float* Wb = (const float*)d_in[9];
  const float* bb = (const float*)d_in[10];
  const float* cq = (const float*)d_in[11];
  const float* ck = (const float*)d_in[12];
  const float* cv = (const float*)d_in[13];
  const float* Wo = (const float*)d_in[14];
  const float* bo = (const float*)d_in[15];
  float* out = (float*)d_out;
  float* ws  = (float*)d_ws;

  const size_t per_b = (size_t)SEQ * DIMC;  // 2,097,152 floats

  // choose batch chunk so workspace fits: 4 big bufs + ab + packed Wab
  int bc = BATCH;
  while (bc > 1) {
    size_t need = (4 * (size_t)bc * per_b + (size_t)bc * SEQ * 32 + 128 * 1024 + 128) * sizeof(float);
    if (need <= ws_size) break;
    bc >>= 1;
  }

  float* P   = ws;
  float* qb  = P  + (size_t)bc * per_b;
  float* kb  = qb + (size_t)bc * per_b;
  float* vb  = kb + (size_t)bc * per_b;
  float* abb = vb + (size_t)bc * per_b;
  float* Wab = abb + (size_t)bc * SEQ * 32;
  float* bab = Wab + 128 * 1024;

  pack_ab_kernel<<<513, 256, 0, stream>>>(Wa, ba, Wb, bb, Wab, bab);

  for (int b0 = 0; b0 < BATCH; b0 += bc) {
    const float* xb = x + (size_t)b0 * per_b;
    const int M = bc * SEQ;
    dim3 gg(M / BM, DIMC / BN);
    dim3 gab(M / BM, 1);

    // q path
    sgemm_kernel<<<gg, 256, 0, stream>>>(xb, Wq, bq, P, DIMC, DIMC, DIMC, 1);
    conv_kernel<<<dim3(M), 256, 0, stream>>>(P, cq, qb, 1);
    // k path
    sgemm_kernel<<<gg, 256, 0, stream>>>(xb, Wk, bk, P, DIMC, DIMC, DIMC, 1);
    conv_kernel<<<dim3(M), 256, 0, stream>>>(P, ck, kb, 1);
    // v path
    sgemm_kernel<<<gg, 256, 0, stream>>>(xb, Wv, bv, P, DIMC, DIMC, DIMC, 1);
    conv_kernel<<<dim3(M), 256, 0, stream>>>(P, cv, vb, 0);
    // gates a,b  (padded 128-col GEMM, only first 32 written, sigmoid)
    sgemm_kernel<<<gab, 256, 0, stream>>>(xb, Wab, bab, abb, DIMC, 32, 32, 2);
    // recurrence -> O (reuse P)
    scan_kernel<<<dim3(bc * NHEAD), 256, 0, stream>>>(qb, kb, vb, abb, P);
    // output projection
    sgemm_kernel<<<gg, 256, 0, stream>>>(P, Wo, bo, out + (size_t)b0 * per_b, DIMC, DIMC, DIMC, 0);
  }
}

// Round 3
// 3220.582 us; speedup vs baseline: 1.4847x; 1.4847x over previous
//
#include <hip/hip_runtime.h>

#define DIMC 1024
#define SEQ  2048
#define NHEAD 16
#define BATCH 8

// ---------------------------------------------------------------- helpers
__device__ __forceinline__ void gll4(const float* g, float* l) {
  __builtin_amdgcn_global_load_lds(
      (const __attribute__((address_space(1))) void*)g,
      (__attribute__((address_space(3))) void*)l, 4, 0, 0);
}
__device__ __forceinline__ void gll16(const unsigned short* g, unsigned short* l) {
  __builtin_amdgcn_global_load_lds(
      (const __attribute__((address_space(1))) void*)g,
      (__attribute__((address_space(3))) void*)l, 16, 0, 0);
}

// waitcnt immediates (gfx9 encoding: vm[3:0]=b3:0, exp=b6:4, lgkm=b11:8, vm[5:4]=b15:14)
#define WAIT_VM21   0x4F75  // vmcnt<=21 (ring depth math: 3*(PD-1))
#define WAIT_VM0    0x0F70  // vmcnt<=0
#define WAIT_LGKM0  0xC07F  // lgkmcnt<=0 only

// fp32 <-> bf16 (RNE)
__device__ __forceinline__ unsigned short f2bf(float f) {
  unsigned u = __float_as_uint(f);
  return (unsigned short)((u + 0x7fffu + ((u >> 16) & 1u)) >> 16);
}
__device__ __forceinline__ float bf2f(unsigned short h) {
  return __uint_as_float(((unsigned)h) << 16);
}

typedef __attribute__((ext_vector_type(8))) short  bf16x8;
typedef __attribute__((ext_vector_type(4))) float  floatx4;

// ---------------------------------------------------------------- split fp32 -> bf16 hi/lo
__global__ __launch_bounds__(256)
void cvt_split(const float* __restrict__ in, unsigned short* __restrict__ hi,
               unsigned short* __restrict__ lo, int n4)
{
  int i = blockIdx.x * 256 + threadIdx.x;
  if (i >= n4) return;
  float4 f = ((const float4*)in)[i];
  unsigned short h0 = f2bf(f.x), h1 = f2bf(f.y), h2 = f2bf(f.z), h3 = f2bf(f.w);
  unsigned short l0 = f2bf(f.x - bf2f(h0)), l1 = f2bf(f.y - bf2f(h1));
  unsigned short l2 = f2bf(f.z - bf2f(h2)), l3 = f2bf(f.w - bf2f(h3));
  ushort4 H; H.x = h0; H.y = h1; H.z = h2; H.w = h3;
  ushort4 L; L.x = l0; L.y = l1; L.z = l2; L.w = l3;
  ((ushort4*)hi)[i] = H;
  ((ushort4*)lo)[i] = L;
}

// ---------------------------------------------------------------- pack Wa/Wb into padded 128x1024
__global__ void pack_ab_kernel(const float* __restrict__ Wa, const float* __restrict__ ba,
                               const float* __restrict__ Wb, const float* __restrict__ bb,
                               float* __restrict__ Wab, float* __restrict__ bab)
{
  int i = blockIdx.x * 256 + threadIdx.x;
  if (i < 128 * 1024) {
    int row = i >> 10, col = i & 1023;
    float v = 0.0f;
    if (row < 16) v = Wa[(row << 10) + col];
    else if (row < 32) v = Wb[((row - 16) << 10) + col];
    Wab[i] = v;
  } else {
    int j = i - 128 * 1024;
    if (j < 128) {
      float v = 0.0f;
      if (j < 16) v = ba[j];
      else if (j < 32) v = bb[j - 16];
      bab[j] = v;
    }
  }
}

// ---------------------------------------------------------------- split-bf16 MFMA GEMM
// C[M,N] = act(A @ B^T + bias), A: MxK (bf16 hi/lo), B: NxK (bf16 hi/lo), fp32 out.
// Emulates fp32 via Ah*Bh + Ah*Bl + Al*Bh (3 MFMAs per tile pair).
// m97 structure: 128x128 tile, BK=32, global_load_lds(16B), 2-barrier K-loop.
__global__ __launch_bounds__(256, 2)
void gemm_bf16x3(const unsigned short* __restrict__ Ah, const unsigned short* __restrict__ Al,
                 const unsigned short* __restrict__ Bh, const unsigned short* __restrict__ Bl,
                 const float* __restrict__ bias, float* __restrict__ C,
                 int K, int ldc, int nvalid, int act)
{
  __shared__ unsigned short sAh[4096], sAl[4096], sBh[4096], sBl[4096]; // 128 rows x 32 k, 8KB each
  const int tid  = threadIdx.x;
  const int lane = tid & 63;
  const int w    = tid >> 6;

  // staging: tile = 512 chunks of 16B; round0 chunk = tid (row=tid>>2,k8=tid&3), round1 = tid+256
  const int crow = tid >> 2;            // 0..63
  const int kel  = (tid & 3) << 3;      // 0,8,16,24
  const unsigned short* pAh0 = Ah + (size_t)(blockIdx.x * 128 + crow) * K + kel;
  const unsigned short* pAh1 = Ah + (size_t)(blockIdx.x * 128 + 64 + crow) * K + kel;
  const unsigned short* pAl0 = Al + (size_t)(blockIdx.x * 128 + crow) * K + kel;
  const unsigned short* pAl1 = Al + (size_t)(blockIdx.x * 128 + 64 + crow) * K + kel;
  const unsigned short* pBh0 = Bh + (size_t)(blockIdx.y * 128 + crow) * K + kel;
  const unsigned short* pBh1 = Bh + (size_t)(blockIdx.y * 128 + 64 + crow) * K + kel;
  const unsigned short* pBl0 = Bl + (size_t)(blockIdx.y * 128 + crow) * K + kel;
  const unsigned short* pBl1 = Bl + (size_t)(blockIdx.y * 128 + 64 + crow) * K + kel;
  const int wb = (tid & 192) * 8;       // wave-uniform LDS base (elements), = (tid>>6)*512

  floatx4 acc[16];
  #pragma unroll
  for (int i = 0; i < 16; ++i) acc[i] = (floatx4){0.f, 0.f, 0.f, 0.f};

  const int mq = (w & 1) << 6;          // wave quadrant
  const int nq = (w >> 1) << 6;
  const int fr = lane & 15;             // frag row
  const int fk = (lane >> 4) << 3;      // frag k offset

  for (int kt = 0; kt < K; kt += 32) {
    __syncthreads();                    // prev iter done reading LDS
    gll16(pAh0, sAh + wb); gll16(pAh1, sAh + 2048 + wb);
    gll16(pAl0, sAl + wb); gll16(pAl1, sAl + 2048 + wb);
    gll16(pBh0, sBh + wb); gll16(pBh1, sBh + 2048 + wb);
    gll16(pBl0, sBl + wb); gll16(pBl1, sBl + 2048 + wb);
    pAh0 += 32; pAh1 += 32; pAl0 += 32; pAl1 += 32;
    pBh0 += 32; pBh1 += 32; pBl0 += 32; pBl1 += 32;
    __syncthreads();                    // implies vmcnt(0) drain -> tiles ready

    bf16x8 ah[4], al[4], bh[4], bl[4];
    #pragma unroll
    for (int mi = 0; mi < 4; ++mi) {
      int off = (mq + mi * 16 + fr) * 32 + fk;
      ah[mi] = *(const bf16x8*)&sAh[off];
      al[mi] = *(const bf16x8*)&sAl[off];
    }
    #pragma unroll
    for (int ni = 0; ni < 4; ++ni) {
      int off = (nq + ni * 16 + fr) * 32 + fk;
      bh[ni] = *(const bf16x8*)&sBh[off];
      bl[ni] = *(const bf16x8*)&sBl[off];
    }
    #pragma unroll
    for (int mi = 0; mi < 4; ++mi)
      #pragma unroll
      for (int ni = 0; ni < 4; ++ni) {
        floatx4 c = acc[mi * 4 + ni];
        c = __builtin_amdgcn_mfma_f32_16x16x32_bf16(ah[mi], bh[ni], c, 0, 0, 0);
        c = __builtin_amdgcn_mfma_f32_16x16x32_bf16(ah[mi], bl[ni], c, 0, 0, 0);
        c = __builtin_amdgcn_mfma_f32_16x16x32_bf16(al[mi], bh[ni], c, 0, 0, 0);
        acc[mi * 4 + ni] = c;
      }
  }

  // C/D layout (m89-verified): n = lane&15, m = (lane>>4)*4 + reg
  const int mbase = blockIdx.x * 128 + mq + ((lane >> 4) << 2);
  const int nbase = blockIdx.y * 128 + nq + (lane & 15);
  #pragma unroll
  for (int ni = 0; ni < 4; ++ni) {
    int n = nbase + ni * 16;
    if (n < nvalid) {
      float bs = bias[n];
      #pragma unroll
      for (int mi = 0; mi < 4; ++mi) {
        #pragma unroll
        for (int r = 0; r < 4; ++r) {
          int m = mbase + mi * 16 + r;
          float val = acc[mi * 4 + ni][r] + bs;
          if (act == 1)      val = val * (1.0f / (1.0f + __expf(-val)));   // silu
          else if (act == 2) val = 1.0f / (1.0f + __expf(-val));            // sigmoid
          C[(size_t)m * ldc + n] = val;
        }
      }
    }
  }
}

// ---------------------------------------------------------------- depthwise conv(K=4,pad2) + silu + optional l2norm
__global__ __launch_bounds__(256)
void conv_kernel(const float* __restrict__ pre, const float* __restrict__ w,
                 float* __restrict__ out, int do_norm)
{
  __shared__ float red[4];
  const int bt  = blockIdx.x;
  const int t   = bt & (SEQ - 1);
  const int tid = threadIdx.x;
  const int c   = tid << 2;
  const float* rowp = pre + (size_t)bt * DIMC + c;
  const float4 z = make_float4(0.f, 0.f, 0.f, 0.f);
  float4 xm2 = (t >= 2)      ? *(const float4*)(rowp - 2 * DIMC) : z;
  float4 xm1 = (t >= 1)      ? *(const float4*)(rowp - DIMC)     : z;
  float4 x0  =                 *(const float4*)(rowp);
  float4 xp1 = (t + 1 < SEQ) ? *(const float4*)(rowp + DIMC)     : z;
  const float4 w0 = *(const float4*)(w + (size_t)(c + 0) * 4);
  const float4 w1 = *(const float4*)(w + (size_t)(c + 1) * 4);
  const float4 w2 = *(const float4*)(w + (size_t)(c + 2) * 4);
  const float4 w3 = *(const float4*)(w + (size_t)(c + 3) * 4);
  float y0 = xm2.x * w0.x + xm1.x * w0.y + x0.x * w0.z + xp1.x * w0.w;
  float y1 = xm2.y * w1.x + xm1.y * w1.y + x0.y * w1.z + xp1.y * w1.w;
  float y2 = xm2.z * w2.x + xm1.z * w2.y + x0.z * w2.z + xp1.z * w2.w;
  float y3 = xm2.w * w3.x + xm1.w * w3.y + x0.w * w3.z + xp1.w * w3.w;
  y0 = y0 * (1.0f / (1.0f + __expf(-y0)));
  y1 = y1 * (1.0f / (1.0f + __expf(-y1)));
  y2 = y2 * (1.0f / (1.0f + __expf(-y2)));
  y3 = y3 * (1.0f / (1.0f + __expf(-y3)));
  if (do_norm) {
    float ss = y0*y0 + y1*y1 + y2*y2 + y3*y3;
    #pragma unroll
    for (int off = 32; off >= 1; off >>= 1) ss += __shfl_xor(ss, off);
    if ((tid & 63) == 0) red[tid >> 6] = ss;
    __syncthreads();
    float tot = red[0] + red[1] + red[2] + red[3];
    float rn = 1.0f / (sqrtf(tot) + 1e-6f);
    y0 *= rn; y1 *= rn; y2 *= rn; y3 *= rn;
  }
  *(float4*)(out + (size_t)bt * DIMC + c) = make_float4(y0, y1, y2, y3);
}

// ---------------------------------------------------------------- gated delta scan (unchanged from round 2)
#define PD 8
__global__ __launch_bounds__(256, 1)
void scan_kernel(const float* __restrict__ q, const float* __restrict__ k,
                 const float* __restrict__ v, const float* __restrict__ ab,
                 float* __restrict__ O)
{
  __shared__ float ring[PD][3][64];
  __shared__ float coefs[2][64];
  __shared__ float aS[SEQ];
  __shared__ float bSh[SEQ];
  const int bh  = blockIdx.x;
  const int b   = bh >> 4, h = bh & 15;
  const int tid = threadIdx.x;
  const int r   = tid >> 2, g = tid & 3;
  const int lane = tid & 63;

  const float* abbase = ab + (size_t)b * SEQ * 32 + h;
  for (int i = tid; i < SEQ; i += 256) {
    aS[i]  = abbase[(size_t)i * 32];
    bSh[i] = abbase[(size_t)i * 32 + 16];
  }
  __syncthreads();

  const size_t base = (size_t)b * SEQ * DIMC + h * 64;
  const float* qp = q + base + lane;
  const float* kp = k + base + lane;
  const float* vp = v + base + lane;

  #pragma unroll
  for (int pt = 0; pt < PD; ++pt) {
    gll4(qp + (size_t)pt * DIMC, &ring[pt][0][0]);
    gll4(kp + (size_t)pt * DIMC, &ring[pt][1][0]);
    gll4(vp + (size_t)pt * DIMC, &ring[pt][2][0]);
  }

  float S[16], T[16];
  #pragma unroll
  for (int j = 0; j < 16; ++j) { S[j] = 0.f; T[j] = 0.f; }
  float* Ob = O + base;
  int p = 0;

  for (int t = 0; t < SEQ; ++t) {
    const int slot = t & (PD - 1);
    if (t < SEQ - PD) { __builtin_amdgcn_s_waitcnt(WAIT_VM21); }
    else              { __builtin_amdgcn_s_waitcnt(WAIT_VM0);  }
    asm volatile("" ::: "memory");

    const float a  = aS[t];
    const float bg = bSh[t];
    const float4 k0 = *(const float4*)&ring[slot][1][(g << 4) + 0];
    const float4 k1 = *(const float4*)&ring[slot][1][(g << 4) + 4];
    const float4 k2 = *(const float4*)&ring[slot][1][(g << 4) + 8];
    const float4 k3 = *(const float4*)&ring[slot][1][(g << 4) + 12];
    const float4 q0 = *(const float4*)&ring[slot][0][(g << 4) + 0];
    const float4 q1 = *(const float4*)&ring[slot][0][(g << 4) + 4];
    const float4 q2 = *(const float4*)&ring[slot][0][(g << 4) + 8];
    const float4 q3 = *(const float4*)&ring[slot][0][(g << 4) + 12];
    const float vd = ring[slot][2][r];
    const float ke = ring[slot][1][r];
    const float kk[16] = {k0.x,k0.y,k0.z,k0.w, k1.x,k1.y,k1.z,k1.w,
                          k2.x,k2.y,k2.z,k2.w, k3.x,k3.y,k3.z,k3.w};
    const float qq[16] = {q0.x,q0.y,q0.z,q0.w, q1.x,q1.y,q1.z,q1.w,
                          q2.x,q2.y,q2.z,q2.w, q3.x,q3.y,q3.z,q3.w};

    float sk = 0.f;
    #pragma unroll
    for (int j = 0; j < 16; ++j) sk = fmaf(S[j], kk[j], sk);
    sk += __shfl_xor(sk, 1);
    sk += __shfl_xor(sk, 2);
    const float coef = bg * vd - a * bg * sk;
    if (g == 0) coefs[p][r] = coef;

    asm volatile("" ::: "memory");
    __builtin_amdgcn_s_waitcnt(WAIT_LGKM0);
    __builtin_amdgcn_s_barrier();
    asm volatile("" ::: "memory");

    if (t + PD < SEQ) {
      gll4(qp + (size_t)(t + PD) * DIMC, &ring[slot][0][0]);
      gll4(kp + (size_t)(t + PD) * DIMC, &ring[slot][1][0]);
      gll4(vp + (size_t)(t + PD) * DIMC, &ring[slot][2][0]);
    }

    const float4 c0 = *(const float4*)&coefs[p][(g << 4) + 0];
    const float4 c1 = *(const float4*)&coefs[p][(g << 4) + 4];
    const float4 c2 = *(const float4*)&coefs[p][(g << 4) + 8];
    const float4 c3 = *(const float4*)&coefs[p][(g << 4) + 12];
    const float cc[16] = {c0.x,c0.y,c0.z,c0.w, c1.x,c1.y,c1.z,c1.w,
                          c2.x,c2.y,c2.z,c2.w, c3.x,c3.y,c3.z,c3.w};
    float o = 0.f;
    #pragma unroll
    for (int j = 0; j < 16; ++j) {
      S[j] = fmaf(a, S[j], coef * kk[j]);
      float tj = fmaf(a, T[j], ke * cc[j]);
      T[j] = tj;
      o = fmaf(qq[j], tj, o);
    }
    o += __shfl_xor(o, 1);
    o += __shfl_xor(o, 2);
    if (g == 0) Ob[(size_t)t * DIMC + r] = o;
    p ^= 1;
  }
}

// ---------------------------------------------------------------- host
extern "C" void kernel_launch(void* const* d_in, const int* in_sizes, int n_in,
                              void* d_out, int out_size, void* d_ws, size_t ws_size,
                              hipStream_t stream)
{
  const float* x  = (const float*)d_in[0];
  const float* Wq = (const float*)d_in[1];
  const float* bq = (const float*)d_in[2];
  const float* Wk = (const float*)d_in[3];
  const float* bk = (const float*)d_in[4];
  const float* Wv = (const float*)d_in[5];
  const float* bv = (const float*)d_in[6];
  const float* Wa = (const float*)d_in[7];
  const float* ba = (const float*)d_in[8];
  const float* Wb = (const float*)d_in[9];
  const float* bb = (const float*)d_in[10];
  const float* cq = (const float*)d_in[11];
  const float* ck = (const float*)d_in[12];
  const float* cv = (const float*)d_in[13];
  const float* Wo = (const float*)d_in[14];
  const float* bo = (const float*)d_in[15];
  float* out = (float*)d_out;
  float* ws  = (float*)d_ws;

  const size_t per_b = (size_t)SEQ * DIMC;     // 2,097,152
  const size_t wsz   = (size_t)DIMC * DIMC;    // 1,048,576

  // workspace: floats [P,qb,kb,vb,abb,Wab,bab] then ushorts [xh,xl, weight hi/lo x5]
  int bc = BATCH;
  while (bc > 1) {
    size_t fl = 4 * (size_t)bc * per_b + (size_t)bc * SEQ * 32 + 128 * 1024 + 128;
    size_t us = 2 * (size_t)bc * per_b + 8 * wsz + 2 * 128 * 1024;
    if (fl * 4 + us * 2 <= ws_size) break;
    bc >>= 1;
  }

  float* P   = ws;
  float* qb  = P  + (size_t)bc * per_b;
  float* kb  = qb + (size_t)bc * per_b;
  float* vb  = kb + (size_t)bc * per_b;
  float* abb = vb + (size_t)bc * per_b;
  float* Wab = abb + (size_t)bc * SEQ * 32;
  float* bab = Wab + 128 * 1024;
  unsigned short* xh   = (unsigned short*)(bab + 128);
  unsigned short* xl   = xh  + (size_t)bc * per_b;
  unsigned short* wqh  = xl  + (size_t)bc * per_b;
  unsigned short* wql  = wqh + wsz;
  unsigned short* wkh  = wql + wsz;
  unsigned short* wkl  = wkh + wsz;
  unsigned short* wvh  = wkl + wsz;
  unsigned short* wvl  = wvh + wsz;
  unsigned short* woh  = wvl + wsz;
  unsigned short* wol  = woh + wsz;
  unsigned short* wabh = wol + wsz;
  unsigned short* wabl = wabh + 128 * 1024;

  pack_ab_kernel<<<513, 256, 0, stream>>>(Wa, ba, Wb, bb, Wab, bab);
  cvt_split<<<(int)(wsz / 4 + 255) / 256, 256, 0, stream>>>(Wq, wqh, wql, (int)(wsz / 4));
  cvt_split<<<(int)(wsz / 4 + 255) / 256, 256, 0, stream>>>(Wk, wkh, wkl, (int)(wsz / 4));
  cvt_split<<<(int)(wsz / 4 + 255) / 256, 256, 0, stream>>>(Wv, wvh, wvl, (int)(wsz / 4));
  cvt_split<<<(int)(wsz / 4 + 255) / 256, 256, 0, stream>>>(Wo, woh, wol, (int)(wsz / 4));
  cvt_split<<<(128 * 1024 / 4 + 255) / 256, 256, 0, stream>>>(Wab, wabh, wabl, 128 * 1024 / 4);

  for (int b0 = 0; b0 < BATCH; b0 += bc) {
    const float* xb = x + (size_t)b0 * per_b;
    const int M = bc * SEQ;
    const int n4 = (int)((size_t)bc * per_b / 4);
    dim3 gg(M / 128, DIMC / 128);
    dim3 gab(M / 128, 1);

    cvt_split<<<(n4 + 255) / 256, 256, 0, stream>>>(xb, xh, xl, n4);

    // q path
    gemm_bf16x3<<<gg, 256, 0, stream>>>(xh, xl, wqh, wql, bq, P, DIMC, DIMC, DIMC, 1);
    conv_kernel<<<dim3(M), 256, 0, stream>>>(P, cq, qb, 1);
    // k path
    gemm_bf16x3<<<gg, 256, 0, stream>>>(xh, xl, wkh, wkl, bk, P, DIMC, DIMC, DIMC, 1);
    conv_kernel<<<dim3(M), 256, 0, stream>>>(P, ck, kb, 1);
    // v path
    gemm_bf16x3<<<gg, 256, 0, stream>>>(xh, xl, wvh, wvl, bv, P, DIMC, DIMC, DIMC, 1);
    conv_kernel<<<dim3(M), 256, 0, stream>>>(P, cv, vb, 0);
    // gates (padded 128-wide GEMM, 32 valid cols, sigmoid)
    gemm_bf16x3<<<gab, 256, 0, stream>>>(xh, xl, wabh, wabl, bab, abb, DIMC, 32, 32, 2);
    // recurrence -> P
    scan_kernel<<<dim3(bc * NHEAD), 256, 0, stream>>>(qb, kb, vb, abb, P);
    // output projection: reuse xh/xl as O hi/lo
    cvt_split<<<(n4 + 255) / 256, 256, 0, stream>>>(P, xh, xl, n4);
    gemm_bf16x3<<<gg, 256, 0, stream>>>(xh, xl, woh, wol, bo, out + (size_t)b0 * per_b, DIMC, DIMC, DIMC, 0);
  }
}